// Round 1
// baseline (185.869 us; speedup 1.0000x reference)
//
#include <hip/hip_runtime.h>
#include <math.h>

// Problem constants: B=2, C=256, DM=512, H=8, D=64, SPARSE_K=64
typedef __bf16 bf16;
typedef __attribute__((ext_vector_type(4))) __bf16 bf16x4;
typedef __attribute__((ext_vector_type(8))) __bf16 bf16x8;
typedef __attribute__((ext_vector_type(4))) float floatx4;
typedef __attribute__((ext_vector_type(2))) float f32x2;

__device__ __forceinline__ f32x2 mk2(float a, float b) { f32x2 r; r.x = a; r.y = b; return r; }
__device__ __forceinline__ f32x2 sp2(float a) { f32x2 r; r.x = a; r.y = a; return r; }

// ---------------------------------------------------------------------------
// Packed-pair exact gelu: 6-term Taylor erf on |t|<=0.5 (abs err <= 1.5e-8),
// erff fallback for rare outliers. Operates on a register PAIR so the poly
// chain lowers to v_pk_fma_f32 (full-rate packed fp32 on CDNA4).
// ---------------------------------------------------------------------------
__device__ __forceinline__ f32x2 gelu2(f32x2 x) {
    f32x2 tt = x * 0.70710678118654752440f;
    f32x2 s  = tt * tt;
    f32x2 p  = __builtin_elementwise_fma(s, sp2(-8.548327023450852e-4f), sp2(5.223977625442188e-3f));
    p = __builtin_elementwise_fma(s, p, sp2(-2.6866170645131252e-2f));
    p = __builtin_elementwise_fma(s, p, sp2(0.11283791670955126f));
    p = __builtin_elementwise_fma(s, p, sp2(-0.3761263890318375f));
    p = __builtin_elementwise_fma(s, p, sp2(1.1283791670955126f));
    f32x2 e = tt * p;
    if (__builtin_expect(fabsf(tt.x) > 0.5f, 0)) e.x = erff(tt.x);
    if (__builtin_expect(fabsf(tt.y) > 0.5f, 0)) e.y = erff(tt.y);
    f32x2 hx = x * 0.5f;
    return __builtin_elementwise_fma(hx, e, hx);   // 0.5x + 0.5x*e
}

__device__ __forceinline__ void split3(float a, bf16& h, bf16& m, bf16& l) {
    h = (bf16)a;  float r1 = a - (float)h;
    m = (bf16)r1; float r2 = r1 - (float)m;
    l = (bf16)r2;
}

// ---------------------------------------------------------------------------
// Triple-split into MFMA frag-major order for [512][512] matrices; 5 matrices
// batched via blockIdx.z. (row,k) -> ((rt*16+ks)*64 + q4*16 + rm)*8 + u.
// ---------------------------------------------------------------------------
struct SplitArgs {
    const float* src[5];
    bf16* h[5]; bf16* m[5]; bf16* l[5];
};

__global__ __launch_bounds__(256) void split3_512_kernel(SplitArgs S) {
    int z = blockIdx.z;
    const float* src = S.src[z];
    bf16* dh = S.h[z]; bf16* dm = S.m[z]; bf16* dl = S.l[z];
    int t = blockIdx.x * 256 + threadIdx.x;
    int row = t >> 7, kq = (t & 127) * 4;
    int rt = row >> 4, rm = row & 15;
    int ks = kq >> 5, q4 = (kq >> 3) & 3, u0 = kq & 7;
    int dst = ((rt * 16 + ks) * 64 + q4 * 16 + rm) * 8 + u0;
    float4 vv = *(const float4*)&src[row * 512 + kq];
    float a4[4] = {vv.x, vv.y, vv.z, vv.w};
    bf16x4 h, m, l;
    #pragma unroll
    for (int u = 0; u < 4; u++) {
        bf16 hh, mm, ll;
        split3(a4[u], hh, mm, ll);
        h[u] = hh; m[u] = mm; l[u] = ll;
    }
    *(bf16x4*)&dh[dst] = h;
    *(bf16x4*)&dm[dst] = m;
    *(bf16x4*)&dl[dst] = l;
}

// ---------------------------------------------------------------------------
// C = A @ W^T + bias via triple-split bf16 MFMA. One wave per block computing
// a 16(m) x 16(n) tile; grid (32 nx, 32 ny, nz). R12: the 6 MFMAs per k-step
// are split into TWO independent 3-chains (acc0: *xKh terms, acc1: Ahx*/mm
// terms) — halves the dependent-MFMA latency per k-step at +4 VGPR.
// mode 0: fp32 [m*512+n]; mode 1: heads fp32 (b,h,c,d); mode 2: K written
// directly as frag-major split triple.
// ---------------------------------------------------------------------------
struct MM2Args {
    const bf16 *Ah, *Am, *Al;
    const bf16 *Wh[3], *Wm[3], *Wl[3];
    const float* bias[3];
    float* outf[3];
    bf16 *kh, *km, *kl;
    int mode[3];
};

__global__ __launch_bounds__(64) void mm_mfma_kernel(MM2Args A) {
    const int z = blockIdx.z;
    const bf16* Wh = A.Wh[z]; const bf16* Wm = A.Wm[z]; const bf16* Wl = A.Wl[z];
    const float* bias = A.bias[z];
    const int lane = threadIdx.x;
    const int m16 = lane & 15, q4 = lane >> 4;
    const int mt = blockIdx.y, bx = blockIdx.x;

    floatx4 acc0, acc1;
    {
        float bv = bias[bx * 16 + m16];
        acc0[0] = bv; acc0[1] = bv; acc0[2] = bv; acc0[3] = bv;
        acc1[0] = 0.f; acc1[1] = 0.f; acc1[2] = 0.f; acc1[3] = 0.f;
    }

    #pragma unroll 4
    for (int ks = 0; ks < 16; ks++) {
        int sa = ((mt * 16 + ks) * 64 + lane) * 8;
        bf16x8 ah = *(const bf16x8*)&A.Ah[sa];
        bf16x8 am = *(const bf16x8*)&A.Am[sa];
        bf16x8 al = *(const bf16x8*)&A.Al[sa];
        int sw = ((bx * 16 + ks) * 64 + lane) * 8;
        bf16x8 wh = *(const bf16x8*)&Wh[sw];
        bf16x8 wm = *(const bf16x8*)&Wm[sw];
        bf16x8 wl = *(const bf16x8*)&Wl[sw];
        acc0 = __builtin_amdgcn_mfma_f32_16x16x32_bf16(ah, wh, acc0, 0, 0, 0);
        acc1 = __builtin_amdgcn_mfma_f32_16x16x32_bf16(ah, wm, acc1, 0, 0, 0);
        acc0 = __builtin_amdgcn_mfma_f32_16x16x32_bf16(am, wh, acc0, 0, 0, 0);
        acc1 = __builtin_amdgcn_mfma_f32_16x16x32_bf16(ah, wl, acc1, 0, 0, 0);
        acc0 = __builtin_amdgcn_mfma_f32_16x16x32_bf16(al, wh, acc0, 0, 0, 0);
        acc1 = __builtin_amdgcn_mfma_f32_16x16x32_bf16(am, wm, acc1, 0, 0, 0);
    }
    floatx4 acc = acc0 + acc1;

    const int mode = A.mode[z];
    const int n = bx * 16 + m16;
    #pragma unroll
    for (int r = 0; r < 4; r++) {
        int m = mt * 16 + q4 * 4 + r;
        float val = acc[r];
        if (mode == 0) {
            A.outf[z][m * 512 + n] = val;
        } else if (mode == 1) {
            A.outf[z][(((m >> 8) * 8 + (n >> 6)) * 256 + (m & 255)) * 64 + (n & 63)] = val;
        } else {
            int krow = ((m >> 8) * 8 + (n >> 6)) * 256 + (m & 255);
            int d = n & 63;
            int dst = (((krow >> 4) * 2 + (d >> 5)) * 64 + ((d >> 3) & 3) * 16 + (krow & 15)) * 8 + (d & 7);
            bf16 h, mm, l;
            split3(val, h, mm, l);
            A.kh[dst] = h; A.km[dst] = mm; A.kl[dst] = l;
        }
    }
}

// ---------------------------------------------------------------------------
// Fused per-(bh, i-pair). R12 changes vs the 91.5us R6 kernel:
//  - all dual-query (i0,i1) scalar math packed into f32x2 register pairs so
//    the compiler emits v_pk_fma_f32 / v_pk_min/max_f32 (gelu epilogue, sort
//    compare-exchange, softmax scores, attn@V) — ~30-40% fewer VALU instrs
//  - 12-MFMA serial accumulation chain split into two independent 6-chains
//  - softmax probs stored interleaved (f32x2) so attn@V reads are pair-ready
// ---------------------------------------------------------------------------
__global__ __launch_bounds__(256, 3) void fused_mfma_attn_kernel(
    const float* __restrict__ q, const float* __restrict__ v,
    const bf16* __restrict__ khi, const bf16* __restrict__ kmid, const bf16* __restrict__ klo,
    const float* __restrict__ w1, const float* __restrict__ b1,
    const float* __restrict__ w2, const float* __restrict__ b2,
    bf16* __restrict__ oh, bf16* __restrict__ om, bf16* __restrict__ ol)
{
    const int i2 = blockIdx.x;     // query pair: i = 2*i2 + i01
    const int bh = blockIdx.y;
    const int t  = threadIdx.x;
    const int lane = t & 63, w = t >> 6;
    const int m16 = lane & 15, q4 = lane >> 4;

    __shared__ f32x2 part2[4][256];    // per-wave f-partials of scores (pair = i0,i1)
    __shared__ f32x2 sc2[256];         // softmax probabilities, interleaved (p0,p1)
    __shared__ float qpb_s[2][64];
    __shared__ f32x2 sbuf2[256];       // bitonic cross-wave exchange (pair)
    __shared__ f32x2 red_s[4][64];     // attn@V partials (pair)
    __shared__ f32x2 red2_s[4];
    __shared__ f32x2 thr_s2, smax_s2;

    const int f = w * 16 + m16;         // this lane's f (A-operand M index)
    const float* w1row = w1 + f * 192;

    // ---- build A_i fragments in registers + qpb
    bf16x8 Ah[2][2], Am[2][2], Al[2][2];
    #pragma unroll
    for (int i01 = 0; i01 < 2; i01++) {
        const float* qrow = q + (bh * 256 + i2 * 2 + i01) * 64;
        floatx4 qacc;
        qacc[0] = 0.f; qacc[1] = 0.f; qacc[2] = 0.f; qacc[3] = 0.f;
        #pragma unroll
        for (int ks = 0; ks < 2; ks++) {
            int e0 = ks * 32 + q4 * 8;
            #pragma unroll
            for (int u = 0; u < 2; u++) {
                int e = e0 + u * 4;
                floatx4 wa = *(const floatx4*)&w1row[e];
                floatx4 wb = *(const floatx4*)&w1row[64 + e];
                floatx4 wc = *(const floatx4*)&w1row[128 + e];
                floatx4 qv = *(const floatx4*)&qrow[e];
                qacc = __builtin_elementwise_fma(wa, qv, qacc);          // pk_fma x2
                floatx4 av = __builtin_elementwise_fma(wc, qv, wb);      // pk_fma x2
                #pragma unroll
                for (int uu = 0; uu < 4; uu++) {
                    bf16 h, m, l;
                    split3(av[uu], h, m, l);
                    Ah[i01][ks][u * 4 + uu] = h;
                    Am[i01][ks][u * 4 + uu] = m;
                    Al[i01][ks][u * 4 + uu] = l;
                }
            }
        }
        float qa = (qacc[0] + qacc[1]) + (qacc[2] + qacc[3]);
        qa += __shfl_xor(qa, 16);
        qa += __shfl_xor(qa, 32);
        if (lane < 16) qpb_s[i01][w * 16 + lane] = qa + b1[w * 16 + lane];
    }
    __syncthreads();

    floatx4 qpbr[2];
    qpbr[0] = *(const floatx4*)&qpb_s[0][w * 16 + q4 * 4];
    qpbr[1] = *(const floatx4*)&qpb_s[1][w * 16 + q4 * 4];
    const floatx4 w2f = *(const floatx4*)&w2[w * 16 + q4 * 4];
    const f32x2 w2a = mk2(w2f[0], w2f[1]);
    const f32x2 w2b = mk2(w2f[2], w2f[3]);
    const float b2v = b2[0];

    // ---- main loop over j-tiles: MFMA (two independent 6-chains) + packed epilogue
    #pragma unroll 2
    for (int jt = 0; jt < 16; jt++) {
        int base = ((bh * 16 + jt) * 2 * 64 + lane) * 8;
        bf16x8 Kh0 = *(const bf16x8*)&khi [base];
        bf16x8 Km0 = *(const bf16x8*)&kmid[base];
        bf16x8 Kl0 = *(const bf16x8*)&klo [base];
        bf16x8 Kh1 = *(const bf16x8*)&khi [base + 512];
        bf16x8 Km1 = *(const bf16x8*)&kmid[base + 512];
        bf16x8 Kl1 = *(const bf16x8*)&klo [base + 512];
        f32x2 sp;
        #pragma unroll
        for (int i01 = 0; i01 < 2; i01++) {
            floatx4 a = qpbr[i01];
            floatx4 a2;
            a2[0] = 0.f; a2[1] = 0.f; a2[2] = 0.f; a2[3] = 0.f;
            a  = __builtin_amdgcn_mfma_f32_16x16x32_bf16(Ah[i01][0], Kh0, a,  0, 0, 0);
            a2 = __builtin_amdgcn_mfma_f32_16x16x32_bf16(Ah[i01][0], Km0, a2, 0, 0, 0);
            a  = __builtin_amdgcn_mfma_f32_16x16x32_bf16(Am[i01][0], Kh0, a,  0, 0, 0);
            a2 = __builtin_amdgcn_mfma_f32_16x16x32_bf16(Ah[i01][0], Kl0, a2, 0, 0, 0);
            a  = __builtin_amdgcn_mfma_f32_16x16x32_bf16(Al[i01][0], Kh0, a,  0, 0, 0);
            a2 = __builtin_amdgcn_mfma_f32_16x16x32_bf16(Am[i01][0], Km0, a2, 0, 0, 0);
            a  = __builtin_amdgcn_mfma_f32_16x16x32_bf16(Ah[i01][1], Kh1, a,  0, 0, 0);
            a2 = __builtin_amdgcn_mfma_f32_16x16x32_bf16(Ah[i01][1], Km1, a2, 0, 0, 0);
            a  = __builtin_amdgcn_mfma_f32_16x16x32_bf16(Am[i01][1], Kh1, a,  0, 0, 0);
            a2 = __builtin_amdgcn_mfma_f32_16x16x32_bf16(Ah[i01][1], Kl1, a2, 0, 0, 0);
            a  = __builtin_amdgcn_mfma_f32_16x16x32_bf16(Al[i01][1], Kh1, a,  0, 0, 0);
            a2 = __builtin_amdgcn_mfma_f32_16x16x32_bf16(Am[i01][1], Km1, a2, 0, 0, 0);
            a = a + a2;
            // epilogue: rows of a = 4 f's (q4*4+r), col = j = jt*16+m16
            f32x2 g01 = gelu2(mk2(a[0], a[1]));
            f32x2 g23 = gelu2(mk2(a[2], a[3]));
            f32x2 sv2 = g01 * w2a;
            sv2 = __builtin_elementwise_fma(g23, w2b, sv2);
            float s = sv2.x + sv2.y;
            s += __shfl_xor(s, 16);
            s += __shfl_xor(s, 32);
            sp[i01] = s;
        }
        if (lane < 16) part2[w][jt * 16 + lane] = sp;
    }
    __syncthreads();

    // ---- scores (pair = both queries), packed
    f32x2 score = ((part2[0][t] + part2[1][t]) + (part2[2][t] + part2[3][t]) + b2v) * 0.125f;

    // ---- dual lockstep 256-wide bitonic sort (packed compare-exchange);
    //      sorted[192] = 64th largest.
    f32x2 sv = score;
    #pragma unroll
    for (int k = 2; k <= 256; k <<= 1) {
        #pragma unroll
        for (int j = k >> 1; j >= 1; j >>= 1) {
            f32x2 pv;
            if (j >= 64) {
                sbuf2[t] = sv;
                __syncthreads();
                pv = sbuf2[t ^ j];
                __syncthreads();
            } else {
                pv.x = __shfl_xor(sv.x, j);
                pv.y = __shfl_xor(sv.y, j);
            }
            bool keepMin = (((t & j) == 0) == ((t & k) == 0));
            f32x2 mn = __builtin_elementwise_min(sv, pv);
            f32x2 mx = __builtin_elementwise_max(sv, pv);
            sv = keepMin ? mn : mx;
        }
    }
    if (t == 192) thr_s2  = sv;
    if (t == 255) smax_s2 = sv;
    __syncthreads();

    // ---- softmax numerator + denominator (pair)
    float p0 = (score.x >= thr_s2.x) ? __expf(score.x - smax_s2.x) : 0.0f;
    float p1 = (score.y >= thr_s2.y) ? __expf(score.y - smax_s2.y) : 0.0f;
    sc2[t] = mk2(p0, p1);
    f32x2 ps = mk2(p0, p1);
    #pragma unroll
    for (int mask = 1; mask < 64; mask <<= 1) {
        ps.x += __shfl_xor(ps.x, mask);
        ps.y += __shfl_xor(ps.y, mask);
    }
    if (lane == 0) red2_s[w] = ps;
    __syncthreads();
    f32x2 den = (red2_s[0] + red2_s[1]) + (red2_s[2] + red2_s[3]);
    f32x2 invp;
    invp.x = 1.0f / den.x;
    invp.y = 1.0f / den.y;

    // ---- attn @ V: packed (i0,i1) accumulate, v loads shared between the two i's
    const int d = t & 63, g = t >> 6;
    const float* vb = v + bh * 256 * 64;
    f32x2 av = mk2(0.f, 0.f);
    for (int j4 = 0; j4 < 16; j4++) {
        int jj = g * 64 + j4 * 4;
        f32x2 pp0 = sc2[jj + 0];
        f32x2 pp1 = sc2[jj + 1];
        f32x2 pp2 = sc2[jj + 2];
        f32x2 pp3 = sc2[jj + 3];
        float v0 = vb[(jj + 0) * 64 + d];
        float v1 = vb[(jj + 1) * 64 + d];
        float v2 = vb[(jj + 2) * 64 + d];
        float v3 = vb[(jj + 3) * 64 + d];
        av = __builtin_elementwise_fma(pp0, sp2(v0), av);
        av = __builtin_elementwise_fma(pp1, sp2(v1), av);
        av = __builtin_elementwise_fma(pp2, sp2(v2), av);
        av = __builtin_elementwise_fma(pp3, sp2(v3), av);
    }
    red_s[g][d] = av;
    __syncthreads();

    // ---- output: (B,H,C,D)->(B,C,DM) row, written as split frag-major triple
    if (t < 128) {
        int i01 = t >> 6, dd = t & 63;
        f32x2 osum = (red_s[0][dd] + red_s[1][dd]) + (red_s[2][dd] + red_s[3][dd]);
        float o = (i01 ? osum.y : osum.x) * (i01 ? invp.y : invp.x);
        int b = bh >> 3, h = bh & 7;
        int row = b * 256 + i2 * 2 + i01;
        int n = h * 64 + dd;
        int dst = (((row >> 4) * 16 + (n >> 5)) * 64 + ((n >> 3) & 3) * 16 + (row & 15)) * 8 + (n & 7);
        bf16 hh, mm, ll;
        split3(o, hh, mm, ll);
        oh[dst] = hh; om[dst] = mm; ol[dst] = ll;
    }
}

// ---------------------------------------------------------------------------
extern "C" void kernel_launch(void* const* d_in, const int* in_sizes, int n_in,
                              void* d_out, int out_size, void* d_ws, size_t ws_size,
                              hipStream_t stream) {
    const float* x  = (const float*)d_in[0];
    const float* Wq = (const float*)d_in[1];
    const float* bq = (const float*)d_in[2];
    const float* Wk = (const float*)d_in[3];
    const float* bk = (const float*)d_in[4];
    const float* Wv = (const float*)d_in[5];
    const float* bv = (const float*)d_in[6];
    const float* w1 = (const float*)d_in[7];
    const float* b1 = (const float*)d_in[8];
    const float* w2 = (const float*)d_in[9];
    const float* b2 = (const float*)d_in[10];
    const float* Wo = (const float*)d_in[11];
    const float* bo = (const float*)d_in[12];
    float* out = (float*)d_out;

    const int NE = 262144;   // 512*512
    float* qb  = (float*)d_ws;          // q (b,h,c,d) fp32
    float* vb  = qb + NE;               // v (b,h,c,d) fp32
    bf16* base = (bf16*)(vb + NE);
    bf16* khi  = base;            bf16* kmid = khi + NE;    bf16* klo = kmid + NE;
    bf16* xs   = klo + NE;        // hi/mid/lo triples follow
    bf16* wqs  = xs  + 3 * NE;
    bf16* wks  = wqs + 3 * NE;
    bf16* wvs  = wks + 3 * NE;
    bf16* wos  = wvs + 3 * NE;
    bf16* oas  = wos + 3 * NE;

    // 1) split x, Wq, Wk, Wv, Wo into frag-major bf16 triples
    {
        SplitArgs S;
        const float* srcs[5] = {x, Wq, Wk, Wv, Wo};
        bf16* dsts[5] = {xs, wqs, wks, wvs, wos};
        for (int z = 0; z < 5; z++) {
            S.src[z] = srcs[z];
            S.h[z] = dsts[z]; S.m[z] = dsts[z] + NE; S.l[z] = dsts[z] + 2 * NE;
        }
        split3_512_kernel<<<dim3(256, 1, 5), 256, 0, stream>>>(S);
    }
    // 2) QKV projections; K written directly as split frag-major triple
    {
        MM2Args M;
        M.Ah = xs; M.Am = xs + NE; M.Al = xs + 2 * NE;
        M.Wh[0] = wqs; M.Wm[0] = wqs + NE; M.Wl[0] = wqs + 2 * NE;
        M.Wh[1] = wks; M.Wm[1] = wks + NE; M.Wl[1] = wks + 2 * NE;
        M.Wh[2] = wvs; M.Wm[2] = wvs + NE; M.Wl[2] = wvs + 2 * NE;
        M.bias[0] = bq; M.bias[1] = bk; M.bias[2] = bv;
        M.outf[0] = qb; M.outf[1] = nullptr; M.outf[2] = vb;
        M.kh = khi; M.km = kmid; M.kl = klo;
        M.mode[0] = 1; M.mode[1] = 2; M.mode[2] = 1;
        mm_mfma_kernel<<<dim3(32, 32, 3), 64, 0, stream>>>(M);
    }
    // 3) fused second-order scores + top-64 + softmax + attn@V (+ split out)
    fused_mfma_attn_kernel<<<dim3(128, 16), 256, 0, stream>>>(
        qb, vb, khi, kmid, klo, w1, b1, w2, b2,
        oas, oas + NE, oas + 2 * NE);
    // 4) output projection
    {
        MM2Args M;
        M.Ah = oas; M.Am = oas + NE; M.Al = oas + 2 * NE;
        M.Wh[0] = wos; M.Wm[0] = wos + NE; M.Wl[0] = wos + 2 * NE;
        M.Wh[1] = wos; M.Wm[1] = wos; M.Wl[1] = wos;
        M.Wh[2] = wos; M.Wm[2] = wos; M.Wl[2] = wos;
        M.bias[0] = bo; M.bias[1] = bo; M.bias[2] = bo;
        M.outf[0] = out; M.outf[1] = out; M.outf[2] = out;
        M.kh = khi; M.km = kmid; M.kl = klo;
        M.mode[0] = 0; M.mode[1] = 0; M.mode[2] = 0;
        mm_mfma_kernel<<<dim3(32, 32, 1), 64, 0, stream>>>(M);
    }
}